// Round 9
// baseline (292.849 us; speedup 1.0000x reference)
//
#include <hip/hip_runtime.h>
#include <hip/hip_bf16.h>

typedef __attribute__((ext_vector_type(8))) short bf16x8;  // 8 bf16 (4 VGPR)
typedef __attribute__((ext_vector_type(4))) float f32x4;   // MFMA C/D frag

constexpr int Sc  = 2048;
constexpr int Dc  = 1024;
constexpr int Hc  = 16;
constexpr int HDc = 64;
constexpr int Mc  = 4096;  // B*S

constexpr float ECs = 0.18033688011112042f;  // log2(e)/8, folded into Q

// ---------------------------------------------------------------------------
// bf16 helpers (manual RNE)
// ---------------------------------------------------------------------------
__device__ __forceinline__ ushort f2bf(float f) {
  unsigned u = __float_as_uint(f);
  u += 0x7fffu + ((u >> 16) & 1u);
  return (ushort)(u >> 16);
}
__device__ __forceinline__ float bf2f(ushort h) {
  return __uint_as_float(((unsigned)h) << 16);
}

union US8 {
  ushort u[8];
  uint   w[4];
  bf16x8 v;
};

// ---------------------------------------------------------------------------
// split_x: x fp32 [M,1024] -> bf16 (row-major). 1 float4/thread.
// ---------------------------------------------------------------------------
__global__ __launch_bounds__(256) void split_x_kernel(
    const float* __restrict__ X, ushort* __restrict__ H) {
  const int i    = blockIdx.x * 256 + threadIdx.x;
  const float4 v = ((const float4*)X)[i];
  ushort4 h;
  h.x = f2bf(v.x);
  h.y = f2bf(v.y);
  h.z = f2bf(v.z);
  h.w = f2bf(v.w);
  ((ushort4*)H)[i] = h;
}

// ---------------------------------------------------------------------------
// split_wt: W[k][n] fp32 -> Th/Tl bf16 [n][k] (transpose + hi/lo split).
// z==3 (Wo): lo plane unused downstream -> skip its store.
// ---------------------------------------------------------------------------
struct SplitP {
  const float* W[4];
  ushort*      Th[4];
  ushort*      Tl[4];
};

__global__ __launch_bounds__(256) void split_wt_kernel(SplitP p) {
  __shared__ float T[64][69];
  const int z = blockIdx.z;
  const float* W = p.W[z];
  const int t  = threadIdx.x;
  const int c  = (t & 15) * 4;
  const int r  = t >> 4;
  const int n0 = blockIdx.x * 64, k0 = blockIdx.y * 64;
#pragma unroll
  for (int pp = 0; pp < 4; ++pp) {
    const int k    = r + pp * 16;
    const float4 v = *(const float4*)(W + (size_t)(k0 + k) * 1024 + n0 + c);
    T[k][c + 0] = v.x;
    T[k][c + 1] = v.y;
    T[k][c + 2] = v.z;
    T[k][c + 3] = v.w;
  }
  __syncthreads();
#pragma unroll
  for (int pp = 0; pp < 4; ++pp) {
    const int n = r + pp * 16;
    const float x0 = T[c + 0][n], x1 = T[c + 1][n], x2 = T[c + 2][n], x3 = T[c + 3][n];
    ushort4 h, l;
    h.x = f2bf(x0); l.x = f2bf(x0 - bf2f(h.x));
    h.y = f2bf(x1); l.y = f2bf(x1 - bf2f(h.y));
    h.z = f2bf(x2); l.z = f2bf(x2 - bf2f(h.z));
    h.w = f2bf(x3); l.w = f2bf(x3 - bf2f(h.w));
    *(ushort4*)(p.Th[z] + (size_t)(n0 + n) * 1024 + k0 + c) = h;
    if (z != 3)
      *(ushort4*)(p.Tl[z] + (size_t)(n0 + n) * 1024 + k0 + c) = l;
  }
}

// ---------------------------------------------------------------------------
// bf16 MFMA GEMM, A-operand DIRECT FROM GLOBAL (no A LDS buffer):
// A-frags are row-major 16 B/lane loads, reloaded in-place right after the
// MFMAs that consume them (loads overlap remaining compute + next barrier).
// B staged in LDS with XOR-swizzle (conflict-free, R8-proven).
//  QKV=true : block 128x128, waves 2x2 (wave tile 64x64), 2 products
//             (b_h + b_l); out bf16 [B,H,S,HD]; z selects Wq/Wk/Wv;
//             z==0 pre-scales by log2(e)/8.
//  QKV=false: block 64x128, waves 1x4 (wave tile 64x32), 1 product;
//             out fp32 [M,1024]; grid.x doubled (2 blocks/CU).
// ---------------------------------------------------------------------------
struct GemmP {
  const ushort* Bh[3];
  const ushort* Bl[3];
  const float*  bias[3];
  void*         Out[3];
};

template <bool QKV>
__global__ __launch_bounds__(256) void gemm_bf16(
    const ushort* __restrict__ A, GemmP p) {
  __shared__ __align__(16) ushort BsH[128 * 32];
  __shared__ __align__(16) ushort BsL[QKV ? 128 * 32 : 16];

  constexpr int JT    = QKV ? 4 : 2;    // n-tiles per wave
  constexpr int MROWS = QKV ? 128 : 64; // block m-extent

  const int t  = threadIdx.x;
  const int z  = blockIdx.z;
  const int m0 = blockIdx.x * MROWS, n0 = blockIdx.y * 128;
  const ushort* Bh  = p.Bh[z];
  const ushort* Bl  = p.Bl[z];
  const float* bias = p.bias[z];

  const int lane = t & 63, wave = t >> 6;
  const int wm = QKV ? (wave & 1) * 64 : 0;
  const int wn = QKV ? (wave >> 1) * 64 : wave * 32;

  f32x4 acc[4][JT];
#pragma unroll
  for (int i = 0; i < 4; ++i)
#pragma unroll
    for (int j = 0; j < JT; ++j) acc[i][j] = (f32x4){0.f, 0.f, 0.f, 0.f};

  // B staging: rows {am, am+64}, logical chunk ac, XOR-swizzled slot
  const int am = t >> 2;
  const int ac = t & 3;
  const ushort* gBh = Bh + (size_t)(n0 + am) * 1024 + ac * 8;
  const ushort* gBl = Bl + (size_t)(n0 + am) * 1024 + ac * 8;
  const int sw = ((ac + (am >> 1)) & 3) * 8;
  const int l0 = am * 32 + sw, l1 = (am + 64) * 32 + sw;

  // fragment maps
  const int fr   = lane & 15;
  const int quad = lane >> 4;
  const int fkb  = ((quad + (fr >> 1)) & 3) * 16;  // swizzled byte offset

  // A-frag base: row m0+wm+fr (+16 per i), col quad*8 (+k0)
  const ushort* gA = A + (size_t)(m0 + wm + fr) * 1024 + quad * 8;

  // preload tile k0=0
  bf16x8 fa[4];
#pragma unroll
  for (int i = 0; i < 4; ++i) fa[i] = *(const bf16x8*)(gA + i * 16 * 1024);
  bf16x8 rH0, rH1, rL0, rL1;
  rH0 = *(const bf16x8*)(gBh);
  rH1 = *(const bf16x8*)(gBh + 64 * 1024);
  if (QKV) {
    rL0 = *(const bf16x8*)(gBl);
    rL1 = *(const bf16x8*)(gBl + 64 * 1024);
  }

  for (int k0 = 0; k0 < 1024; k0 += 32) {
    __syncthreads();  // prev compute done reading LDS
    *(bf16x8*)&BsH[l0] = rH0;
    *(bf16x8*)&BsH[l1] = rH1;
    if (QKV) {
      *(bf16x8*)&BsL[l0] = rL0;
      *(bf16x8*)&BsL[l1] = rL1;
    }
    __syncthreads();

    const int  kn   = k0 + 32;
    const bool more = kn < 1024;
    if (more) {  // prefetch B staging for next tile
      rH0 = *(const bf16x8*)(gBh + kn);
      rH1 = *(const bf16x8*)(gBh + kn + 64 * 1024);
      if (QKV) {
        rL0 = *(const bf16x8*)(gBl + kn);
        rL1 = *(const bf16x8*)(gBl + kn + 64 * 1024);
      }
    }

    bf16x8 b_h[JT], b_l[JT];
#pragma unroll
    for (int j = 0; j < JT; ++j) {
      const int rb = (wn + j * 16 + fr) * 64 + fkb;  // bytes
      b_h[j] = *(const bf16x8*)((const char*)BsH + rb);
      if (QKV) b_l[j] = *(const bf16x8*)((const char*)BsL + rb);
    }
#pragma unroll
    for (int i = 0; i < 4; ++i) {
#pragma unroll
      for (int j = 0; j < JT; ++j) {
        acc[i][j] = __builtin_amdgcn_mfma_f32_16x16x32_bf16(fa[i], b_h[j], acc[i][j], 0, 0, 0);
        if (QKV)
          acc[i][j] = __builtin_amdgcn_mfma_f32_16x16x32_bf16(fa[i], b_l[j], acc[i][j], 0, 0, 0);
      }
      // fa[i] consumed -> reload in place for next tile (overlaps compute)
      if (more) fa[i] = *(const bf16x8*)(gA + kn + i * 16 * 1024);
    }
  }

  const float osc = (QKV && z == 0) ? ECs : 1.0f;  // fold softmax scale into Q
  const int cr = quad * 4;
  const int cc = fr;
#pragma unroll
  for (int j = 0; j < JT; ++j) {
    const int n    = n0 + wn + j * 16 + cc;
    const float bv = bias[n];
#pragma unroll
    for (int i = 0; i < 4; ++i) {
      const int mb = m0 + wm + i * 16 + cr;
#pragma unroll
      for (int r = 0; r < 4; ++r) {
        const int m   = mb + r;
        const float v = (acc[i][j][r] + bv) * osc;
        if (QKV) {
          const int b = m >> 11, s = m & 2047, h = n >> 6, hd = n & 63;
          ((ushort*)p.Out[z])[(((size_t)(b * Hc + h) * Sc + s) << 6) + hd] = f2bf(v);
        } else {
          ((float*)p.Out[z])[(size_t)m * 1024 + n] = v;
        }
      }
    }
  }
}

// ---------------------------------------------------------------------------
// MFMA flash attention v4: Q AND K fragments direct from global (register-
// resident / register-prefetched); LDS holds only Vt. S^T = K*Q^T keeps
// scores lane-aligned with the PV A-operand; P stays in registers; V staged
// transposed via v_perm with k-relabeling matched between P and Vt.
// LDS ops/wave/iter: 4 b64 writes + 8 b128 reads (was 22 in R7).
// ---------------------------------------------------------------------------
__global__ __launch_bounds__(256) void attn_mfma4(
    const ushort* __restrict__ Q, const ushort* __restrict__ K,
    const ushort* __restrict__ V, ushort* __restrict__ CTX) {
  __shared__ __align__(16) ushort Vt[64 * 72];  // [d][l(k)]

  const int t    = threadIdx.x;
  const int lane = t & 63, wave = t >> 6;
  const int c16 = lane & 15, quad = lane >> 4;
  const int bh = blockIdx.x, qt = blockIdx.y;
  const int bb = bh >> 4, hh = bh & 15;

  const ushort* Qb = Q + (size_t)bh * Sc * HDc + (size_t)qt * 128 * HDc;
  const ushort* Kb = K + (size_t)bh * Sc * HDc;
  const ushort* Vb = V + (size_t)bh * Sc * HDc;

  // Q B-fragments, register-resident all 32 iterations
  bf16x8 aq[2][2];
#pragma unroll
  for (int mt = 0; mt < 2; ++mt)
#pragma unroll
    for (int c = 0; c < 2; ++c)
      aq[mt][c] = *(const bf16x8*)(Qb + (size_t)(wave * 32 + mt * 16 + c16) * 64 + c * 32 + quad * 8);

  US8 ones_u;
#pragma unroll
  for (int e = 0; e < 8; ++e) ones_u.u[e] = 0x3F80;  // bf16 1.0
  const bf16x8 ones = ones_u.v;

  f32x4 ctx[2][4], lacc[2];
#pragma unroll
  for (int mt = 0; mt < 2; ++mt) {
    lacc[mt] = (f32x4){0.f, 0.f, 0.f, 0.f};
#pragma unroll
    for (int j = 0; j < 4; ++j) ctx[mt][j] = (f32x4){0.f, 0.f, 0.f, 0.f};
  }

  // V staging map (unchanged from R7/R8)
  const int kg = t & 15, dg = t >> 4;
  const int lb = ((kg >> 3) << 5) | ((kg & 3) << 3) | (((kg >> 2) & 1) << 2);
  const ushort* gV = Vb + (size_t)(kg * 4) * 64 + dg * 4;

  // K-frag base: row c16 (+j*16), col quad*8 (+c*32)
  const ushort* gKf = Kb + (size_t)c16 * 64 + quad * 8;

  // preload kt=0
  bf16x8 fk[2][4];
#pragma unroll
  for (int c = 0; c < 2; ++c)
#pragma unroll
    for (int j = 0; j < 4; ++j)
      fk[c][j] = *(const bf16x8*)(gKf + j * 16 * 64 + c * 32);
  ushort4 vr[4];
#pragma unroll
  for (int i = 0; i < 4; ++i) vr[i] = *(const ushort4*)(gV + (size_t)i * 64);

  for (int kt = 0; kt < 32; ++kt) {
    __syncthreads();  // prev PV reads of Vt done
    // commit V: 4x4 ushort transpose via v_perm, b64 rows into Vt[d][l(k)]
    {
      const uint* w0 = (const uint*)&vr[0];
      const uint* w1 = (const uint*)&vr[1];
      const uint* w2 = (const uint*)&vr[2];
      const uint* w3 = (const uint*)&vr[3];
#pragma unroll
      for (int j = 0; j < 4; ++j) {
        const int  wd  = j >> 1;
        const uint sel = (j & 1) ? 0x07060302u : 0x05040100u;
        const uint lo  = __builtin_amdgcn_perm(w1[wd], w0[wd], sel);
        const uint hi  = __builtin_amdgcn_perm(w3[wd], w2[wd], sel);
        *(uint2*)&Vt[(dg * 4 + j) * 72 + lb] = make_uint2(lo, hi);
      }
    }
    __syncthreads();

    // prefetch next V tile into regs
    if (kt < 31) {
      const size_t adv = (size_t)(kt + 1) * 64 * 64;
#pragma unroll
      for (int i = 0; i < 4; ++i) vr[i] = *(const ushort4*)(gV + adv + (size_t)i * 64);
    }

    // S^T = K * Q^T (pure registers)
    f32x4 st[2][4];
#pragma unroll
    for (int mt = 0; mt < 2; ++mt)
#pragma unroll
      for (int j = 0; j < 4; ++j) st[mt][j] = (f32x4){0.f, 0.f, 0.f, 0.f};
#pragma unroll
    for (int c = 0; c < 2; ++c)
#pragma unroll
      for (int j = 0; j < 4; ++j) {
        st[0][j] = __builtin_amdgcn_mfma_f32_16x16x32_bf16(fk[c][j], aq[0][c], st[0][j], 0, 0, 0);
        st[1][j] = __builtin_amdgcn_mfma_f32_16x16x32_bf16(fk[c][j], aq[1][c], st[1][j], 0, 0, 0);
      }

    // fk consumed -> reload in place for next tile (overlaps exp + PV)
    if (kt < 31) {
      const size_t adv = (size_t)(kt + 1) * 64 * 64;
#pragma unroll
      for (int c = 0; c < 2; ++c)
#pragma unroll
        for (int j = 0; j < 4; ++j)
          fk[c][j] = *(const bf16x8*)(gKf + adv + j * 16 * 64 + c * 32);
    }

    // p = exp2(s) (scale pre-folded into Q); pack P A-frags in-register
    US8 pf[2][2];
#pragma unroll
    for (int mt = 0; mt < 2; ++mt)
#pragma unroll
      for (int c2 = 0; c2 < 2; ++c2)
#pragma unroll
        for (int w = 0; w < 4; ++w) {
          const int jj = c2 * 2 + (w >> 1);
          const int r0 = (w & 1) * 2;
          const float pe = __builtin_amdgcn_exp2f(st[mt][jj][r0]);
          const float po = __builtin_amdgcn_exp2f(st[mt][jj][r0 + 1]);
          pf[mt][c2].w[w] = __builtin_amdgcn_perm(
              __float_as_uint(po), __float_as_uint(pe), 0x07060302u);
        }

    // PV + rowsum
#pragma unroll
    for (int c2 = 0; c2 < 2; ++c2) {
      lacc[0] = __builtin_amdgcn_mfma_f32_16x16x32_bf16(pf[0][c2].v, ones, lacc[0], 0, 0, 0);
      lacc[1] = __builtin_amdgcn_mfma_f32_16x16x32_bf16(pf[1][c2].v, ones, lacc[1], 0, 0, 0);
#pragma unroll
      for (int j = 0; j < 4; ++j) {
        const bf16x8 bv = *(const bf16x8*)&Vt[(j * 16 + c16) * 72 + c2 * 32 + quad * 8];
        ctx[0][j] = __builtin_amdgcn_mfma_f32_16x16x32_bf16(pf[0][c2].v, bv, ctx[0][j], 0, 0, 0);
        ctx[1][j] = __builtin_amdgcn_mfma_f32_16x16x32_bf16(pf[1][c2].v, bv, ctx[1][j], 0, 0, 0);
      }
    }
  }

  // epilogue: ctx/l -> bf16 CTX[M,1024]
#pragma unroll
  for (int mt = 0; mt < 2; ++mt) {
#pragma unroll
    for (int r = 0; r < 4; ++r) {
      const float inv = 1.f / lacc[mt][r];
      const int srow  = qt * 128 + wave * 32 + mt * 16 + quad * 4 + r;
      const size_t rb = ((size_t)(bb * Sc + srow)) * 1024 + hh * 64;
#pragma unroll
      for (int j = 0; j < 4; ++j)
        CTX[rb + j * 16 + c16] = f2bf(ctx[mt][j][r] * inv);
    }
  }
}

extern "C" void kernel_launch(void* const* d_in, const int* in_sizes, int n_in,
                              void* d_out, int out_size, void* d_ws, size_t ws_size,
                              hipStream_t stream) {
  (void)in_sizes; (void)n_in; (void)out_size; (void)ws_size;
  const float* x  = (const float*)d_in[0];
  const float* Wq = (const float*)d_in[1];
  const float* bq = (const float*)d_in[2];
  const float* Wk = (const float*)d_in[3];
  const float* bk = (const float*)d_in[4];
  const float* Wv = (const float*)d_in[5];
  const float* bv = (const float*)d_in[6];
  const float* Wo = (const float*)d_in[7];
  const float* bo = (const float*)d_in[8];

  const size_t MB = 1024 * 1024;
  char* w    = (char*)d_ws;
  ushort* Qw = (ushort*)(w + 0 * MB);   // [B,H,S,HD] bf16 (pre-scaled by EC)
  ushort* Kw = (ushort*)(w + 8 * MB);
  ushort* Vw = (ushort*)(w + 16 * MB);
  ushort* Cw = (ushort*)(w + 24 * MB);  // ctx [M,1024] bf16
  ushort* Xh = (ushort*)(w + 32 * MB);  // x bf16 [M,1024]
  ushort* WT = (ushort*)(w + 40 * MB);  // 8 x 2 MB
  ushort* Whq = WT + 0 * 1048576; ushort* Wlq = WT + 1 * 1048576;
  ushort* Whk = WT + 2 * 1048576; ushort* Wlk = WT + 3 * 1048576;
  ushort* Whv = WT + 4 * 1048576; ushort* Wlv = WT + 5 * 1048576;
  ushort* Who = WT + 6 * 1048576; ushort* Wlo = WT + 7 * 1048576;

  const dim3 blk(256);

  split_x_kernel<<<4096, blk, 0, stream>>>(x, Xh);

  SplitP sp;
  sp.W[0] = Wq; sp.W[1] = Wk; sp.W[2] = Wv; sp.W[3] = Wo;
  sp.Th[0] = Whq; sp.Th[1] = Whk; sp.Th[2] = Whv; sp.Th[3] = Who;
  sp.Tl[0] = Wlq; sp.Tl[1] = Wlk; sp.Tl[2] = Wlv; sp.Tl[3] = Wlo;
  split_wt_kernel<<<dim3(16, 16, 4), blk, 0, stream>>>(sp);

  GemmP pq;
  pq.Bh[0] = Whq; pq.Bh[1] = Whk; pq.Bh[2] = Whv;
  pq.Bl[0] = Wlq; pq.Bl[1] = Wlk; pq.Bl[2] = Wlv;
  pq.bias[0] = bq; pq.bias[1] = bk; pq.bias[2] = bv;
  pq.Out[0] = Qw; pq.Out[1] = Kw; pq.Out[2] = Vw;
  gemm_bf16<true><<<dim3(Mc / 128, Dc / 128, 3), blk, 0, stream>>>(Xh, pq);

  attn_mfma4<<<dim3(2 * Hc, Sc / 128), blk, 0, stream>>>(Qw, Kw, Vw, Cw);

  GemmP po;
  po.Bh[0] = po.Bh[1] = po.Bh[2] = Who;
  po.Bl[0] = po.Bl[1] = po.Bl[2] = Wlo;  // unused (1-product)
  po.bias[0] = po.bias[1] = po.bias[2] = bo;
  po.Out[0] = po.Out[1] = po.Out[2] = d_out;
  gemm_bf16<false><<<dim3(Mc / 64, Dc / 128, 1), blk, 0, stream>>>(Cw, po);
}

// Round 10
// 217.374 us; speedup vs baseline: 1.3472x; 1.3472x over previous
//
#include <hip/hip_runtime.h>
#include <hip/hip_bf16.h>

typedef __attribute__((ext_vector_type(8))) short bf16x8;  // 8 bf16 (4 VGPR)
typedef __attribute__((ext_vector_type(4))) float f32x4;   // MFMA C/D frag

constexpr int Sc  = 2048;
constexpr int Dc  = 1024;
constexpr int Hc  = 16;
constexpr int HDc = 64;
constexpr int Mc  = 4096;  // B*S

constexpr float ECs = 0.18033688011112042f;  // log2(e)/8, folded into Q

// ---------------------------------------------------------------------------
// bf16 helpers (manual RNE)
// ---------------------------------------------------------------------------
__device__ __forceinline__ ushort f2bf(float f) {
  unsigned u = __float_as_uint(f);
  u += 0x7fffu + ((u >> 16) & 1u);
  return (ushort)(u >> 16);
}
__device__ __forceinline__ float bf2f(ushort h) {
  return __uint_as_float(((unsigned)h) << 16);
}

union US8 {
  ushort u[8];
  uint   w[4];
  bf16x8 v;
};

// ---------------------------------------------------------------------------
// split_x: x fp32 [M,1024] -> bf16 (row-major). 1 float4/thread.
// ---------------------------------------------------------------------------
__global__ __launch_bounds__(256) void split_x_kernel(
    const float* __restrict__ X, ushort* __restrict__ H) {
  const int i    = blockIdx.x * 256 + threadIdx.x;
  const float4 v = ((const float4*)X)[i];
  ushort4 h;
  h.x = f2bf(v.x);
  h.y = f2bf(v.y);
  h.z = f2bf(v.z);
  h.w = f2bf(v.w);
  ((ushort4*)H)[i] = h;
}

// ---------------------------------------------------------------------------
// split_wt: W[k][n] fp32 -> Th/Tl bf16 [n][k] (transpose + hi/lo split).
// z==3 (Wo): lo plane unused downstream -> skip its store.
// ---------------------------------------------------------------------------
struct SplitP {
  const float* W[4];
  ushort*      Th[4];
  ushort*      Tl[4];
};

__global__ __launch_bounds__(256) void split_wt_kernel(SplitP p) {
  __shared__ float T[64][69];
  const int z = blockIdx.z;
  const float* W = p.W[z];
  const int t  = threadIdx.x;
  const int c  = (t & 15) * 4;
  const int r  = t >> 4;
  const int n0 = blockIdx.x * 64, k0 = blockIdx.y * 64;
#pragma unroll
  for (int pp = 0; pp < 4; ++pp) {
    const int k    = r + pp * 16;
    const float4 v = *(const float4*)(W + (size_t)(k0 + k) * 1024 + n0 + c);
    T[k][c + 0] = v.x;
    T[k][c + 1] = v.y;
    T[k][c + 2] = v.z;
    T[k][c + 3] = v.w;
  }
  __syncthreads();
#pragma unroll
  for (int pp = 0; pp < 4; ++pp) {
    const int n = r + pp * 16;
    const float x0 = T[c + 0][n], x1 = T[c + 1][n], x2 = T[c + 2][n], x3 = T[c + 3][n];
    ushort4 h, l;
    h.x = f2bf(x0); l.x = f2bf(x0 - bf2f(h.x));
    h.y = f2bf(x1); l.y = f2bf(x1 - bf2f(h.y));
    h.z = f2bf(x2); l.z = f2bf(x2 - bf2f(h.z));
    h.w = f2bf(x3); l.w = f2bf(x3 - bf2f(h.w));
    *(ushort4*)(p.Th[z] + (size_t)(n0 + n) * 1024 + k0 + c) = h;
    if (z != 3)
      *(ushort4*)(p.Tl[z] + (size_t)(n0 + n) * 1024 + k0 + c) = l;
  }
}

// ---------------------------------------------------------------------------
// bf16 MFMA GEMM (R8 structure: everything LDS-staged, XOR-swizzled,
// register-prefetch pipeline). XCD-aware grid: blockIdx.x = n-tile (8) so
// XCD = n%8 and each XCD's weight slice (1.5 MB) stays L2-resident.
//  QKV=true : block 128x128, waves 2x2 (tile 64x64), 2 products (b_h+b_l);
//             out bf16 [B,H,S,HD]; z 0..2; z==0 pre-scales by log2(e)/8.
//  QKV=false: block 64x128, waves 1x4 (tile 64x32), 1 product;
//             out fp32 [M,1024]; grid 8x64 (2 blocks/CU).
// ---------------------------------------------------------------------------
struct GemmP {
  const ushort* Bh[3];
  const ushort* Bl[3];
  const float*  bias[3];
  void*         Out[3];
};

template <bool QKV>
__global__ __launch_bounds__(256) void gemm_bf16(
    const ushort* __restrict__ A, GemmP p) {
  constexpr int JT    = QKV ? 4 : 2;    // n-tiles per wave
  constexpr int MROWS = QKV ? 128 : 64; // block m-extent

  __shared__ __align__(16) ushort As[MROWS * 32];
  __shared__ __align__(16) ushort BsH[128 * 32];
  __shared__ __align__(16) ushort BsL[QKV ? 128 * 32 : 16];

  const int t  = threadIdx.x;
  const int z  = blockIdx.z;
  const int n0 = blockIdx.x * 128, m0 = blockIdx.y * MROWS;  // x = n-tile!
  const ushort* Bh  = p.Bh[z];
  const ushort* Bl  = p.Bl[z];
  const float* bias = p.bias[z];

  const int lane = t & 63, wave = t >> 6;
  const int wm = QKV ? (wave & 1) * 64 : 0;
  const int wn = QKV ? (wave >> 1) * 64 : wave * 32;

  f32x4 acc[4][JT];
#pragma unroll
  for (int i = 0; i < 4; ++i)
#pragma unroll
    for (int j = 0; j < JT; ++j) acc[i][j] = (f32x4){0.f, 0.f, 0.f, 0.f};

  // staging: rows {am, am+64}, logical chunk ac, XOR-swizzled slot
  const int am = t >> 2;
  const int ac = t & 3;
  const ushort* gA  = A  + (size_t)(m0 + am) * 1024 + ac * 8;
  const ushort* gBh = Bh + (size_t)(n0 + am) * 1024 + ac * 8;
  const ushort* gBl = Bl + (size_t)(n0 + am) * 1024 + ac * 8;
  const int sw = ((ac + (am >> 1)) & 3) * 8;  // physical elem offset
  const int l0 = am * 32 + sw, l1 = (am + 64) * 32 + sw;

  // fragment maps (swizzle folds to fr only: i*16, wm/wn are even multiples)
  const int fr   = lane & 15;
  const int quad = lane >> 4;
  const int fkb  = ((quad + (fr >> 1)) & 3) * 16;  // swizzled byte offset

  // preload tile k0=0
  bf16x8 rA0, rA1, rH0, rH1, rL0, rL1;
  rA0 = *(const bf16x8*)(gA);
  if (QKV) rA1 = *(const bf16x8*)(gA + 64 * 1024);
  rH0 = *(const bf16x8*)(gBh);
  rH1 = *(const bf16x8*)(gBh + 64 * 1024);
  if (QKV) {
    rL0 = *(const bf16x8*)(gBl);
    rL1 = *(const bf16x8*)(gBl + 64 * 1024);
  }

  for (int k0 = 0; k0 < 1024; k0 += 32) {
    __syncthreads();  // prev compute done reading LDS
    *(bf16x8*)&As[l0]  = rA0;
    if (QKV) *(bf16x8*)&As[l1] = rA1;
    *(bf16x8*)&BsH[l0] = rH0;
    *(bf16x8*)&BsH[l1] = rH1;
    if (QKV) {
      *(bf16x8*)&BsL[l0] = rL0;
      *(bf16x8*)&BsL[l1] = rL1;
    }
    __syncthreads();

    // prefetch next tile (overlaps the whole compute phase; L2-resident
    // weights via the XCD grid mapping keep this ~200 cyc)
    if (k0 + 32 < 1024) {
      const int kn = k0 + 32;
      rA0 = *(const bf16x8*)(gA + kn);
      if (QKV) rA1 = *(const bf16x8*)(gA + kn + 64 * 1024);
      rH0 = *(const bf16x8*)(gBh + kn);
      rH1 = *(const bf16x8*)(gBh + kn + 64 * 1024);
      if (QKV) {
        rL0 = *(const bf16x8*)(gBl + kn);
        rL1 = *(const bf16x8*)(gBl + kn + 64 * 1024);
      }
    }

    bf16x8 a[4], b_h[JT], b_l[JT];
#pragma unroll
    for (int i = 0; i < 4; ++i) {
      const int ra = (wm + i * 16 + fr) * 64 + fkb;  // bytes
      a[i] = *(const bf16x8*)((const char*)As + ra);
    }
#pragma unroll
    for (int j = 0; j < JT; ++j) {
      const int rb = (wn + j * 16 + fr) * 64 + fkb;
      b_h[j] = *(const bf16x8*)((const char*)BsH + rb);
      if (QKV) b_l[j] = *(const bf16x8*)((const char*)BsL + rb);
    }
#pragma unroll
    for (int i = 0; i < 4; ++i)
#pragma unroll
      for (int j = 0; j < JT; ++j) {
        acc[i][j] = __builtin_amdgcn_mfma_f32_16x16x32_bf16(a[i], b_h[j], acc[i][j], 0, 0, 0);
        if (QKV)
          acc[i][j] = __builtin_amdgcn_mfma_f32_16x16x32_bf16(a[i], b_l[j], acc[i][j], 0, 0, 0);
      }
  }

  const float osc = (QKV && z == 0) ? ECs : 1.0f;  // fold softmax scale into Q
  const int cr = quad * 4;
  const int cc = fr;
#pragma unroll
  for (int j = 0; j < JT; ++j) {
    const int n    = n0 + wn + j * 16 + cc;
    const float bv = bias[n];
#pragma unroll
    for (int i = 0; i < 4; ++i) {
      const int mb = m0 + wm + i * 16 + cr;
#pragma unroll
      for (int r = 0; r < 4; ++r) {
        const int m   = mb + r;
        const float v = (acc[i][j][r] + bv) * osc;
        if (QKV) {
          const int b = m >> 11, s = m & 2047, h = n >> 6, hd = n & 63;
          ((ushort*)p.Out[z])[(((size_t)(b * Hc + h) * Sc + s) << 6) + hd] = f2bf(v);
        } else {
          ((float*)p.Out[z])[(size_t)m * 1024 + n] = v;
        }
      }
    }
  }
}

// ---------------------------------------------------------------------------
// MFMA flash attention v3 (R8-proven, verbatim): S^T = K*Q^T so scores land
// lane-aligned with the PV A-operand; P stays in registers; V staged
// transposed via v_perm with k-relabeling; Q frags direct from global
// (contiguous per-lane rows -> coalesced); K/V register-prefetched.
// Grid (bh, qt): XCD = bh%8 -> per-head K/V L2-resident.
// ---------------------------------------------------------------------------
__global__ __launch_bounds__(256) void attn_mfma3(
    const ushort* __restrict__ Q, const ushort* __restrict__ K,
    const ushort* __restrict__ V, ushort* __restrict__ CTX) {
  __shared__ __align__(16) ushort Ks[64 * 72];
  __shared__ __align__(16) ushort Vt[64 * 72];  // [d][l(k)]

  const int t    = threadIdx.x;
  const int lane = t & 63, wave = t >> 6;
  const int c16 = lane & 15, quad = lane >> 4;
  const int bh = blockIdx.x, qt = blockIdx.y;
  const int bb = bh >> 4, hh = bh & 15;

  const ushort* Qb = Q + (size_t)bh * Sc * HDc + (size_t)qt * 128 * HDc;
  const ushort* Kb = K + (size_t)bh * Sc * HDc;
  const ushort* Vb = V + (size_t)bh * Sc * HDc;

  bf16x8 aq[2][2];
#pragma unroll
  for (int mt = 0; mt < 2; ++mt)
#pragma unroll
    for (int c = 0; c < 2; ++c)
      aq[mt][c] = *(const bf16x8*)(Qb + (size_t)(wave * 32 + mt * 16 + c16) * 64 + c * 32 + quad * 8);

  US8 ones_u;
#pragma unroll
  for (int e = 0; e < 8; ++e) ones_u.u[e] = 0x3F80;  // bf16 1.0
  const bf16x8 ones = ones_u.v;

  f32x4 ctx[2][4], lacc[2];
#pragma unroll
  for (int mt = 0; mt < 2; ++mt) {
    lacc[mt] = (f32x4){0.f, 0.f, 0.f, 0.f};
#pragma unroll
    for (int j = 0; j < 4; ++j) ctx[mt][j] = (f32x4){0.f, 0.f, 0.f, 0.f};
  }

  const int krow = t >> 2, kc = (t & 3) * 8;
  const int kg = t & 15, dg = t >> 4;
  const int lb = ((kg >> 3) << 5) | ((kg & 3) << 3) | (((kg >> 2) & 1) << 2);

  const ushort* gK = Kb + (size_t)krow * 64 + kc;
  const ushort* gV = Vb + (size_t)(kg * 4) * 64 + dg * 4;

  bf16x8 kr0, kr1;
  ushort4 vr[4];
  kr0 = *(const bf16x8*)(gK);
  kr1 = *(const bf16x8*)(gK + 32);
#pragma unroll
  for (int i = 0; i < 4; ++i) vr[i] = *(const ushort4*)(gV + (size_t)i * 64);

  for (int kt = 0; kt < 32; ++kt) {
    __syncthreads();
    *(bf16x8*)&Ks[krow * 72 + kc]      = kr0;
    *(bf16x8*)&Ks[krow * 72 + kc + 32] = kr1;
    {
      const uint* w0 = (const uint*)&vr[0];
      const uint* w1 = (const uint*)&vr[1];
      const uint* w2 = (const uint*)&vr[2];
      const uint* w3 = (const uint*)&vr[3];
#pragma unroll
      for (int j = 0; j < 4; ++j) {
        const int  wd  = j >> 1;
        const uint sel = (j & 1) ? 0x07060302u : 0x05040100u;
        const uint lo  = __builtin_amdgcn_perm(w1[wd], w0[wd], sel);
        const uint hi  = __builtin_amdgcn_perm(w3[wd], w2[wd], sel);
        *(uint2*)&Vt[(dg * 4 + j) * 72 + lb] = make_uint2(lo, hi);
      }
    }
    __syncthreads();

    if (kt < 31) {
      const size_t adv = (size_t)(kt + 1) * 64 * 64;
      kr0 = *(const bf16x8*)(gK + adv);
      kr1 = *(const bf16x8*)(gK + adv + 32);
#pragma unroll
      for (int i = 0; i < 4; ++i) vr[i] = *(const ushort4*)(gV + adv + (size_t)i * 64);
    }

    f32x4 st[2][4];
#pragma unroll
    for (int mt = 0; mt < 2; ++mt)
#pragma unroll
      for (int j = 0; j < 4; ++j) st[mt][j] = (f32x4){0.f, 0.f, 0.f, 0.f};
#pragma unroll
    for (int c = 0; c < 2; ++c)
#pragma unroll
      for (int j = 0; j < 4; ++j) {
        const bf16x8 ak = *(const bf16x8*)&Ks[(j * 16 + c16) * 72 + c * 32 + quad * 8];
        st[0][j] = __builtin_amdgcn_mfma_f32_16x16x32_bf16(ak, aq[0][c], st[0][j], 0, 0, 0);
        st[1][j] = __builtin_amdgcn_mfma_f32_16x16x32_bf16(ak, aq[1][c], st[1][j], 0, 0, 0);
      }

    US8 pf[2][2];
#pragma unroll
    for (int mt = 0; mt < 2; ++mt)
#pragma unroll
      for (int c2 = 0; c2 < 2; ++c2)
#pragma unroll
        for (int w = 0; w < 4; ++w) {
          const int jj = c2 * 2 + (w >> 1);
          const int r0 = (w & 1) * 2;
          const float pe = __builtin_amdgcn_exp2f(st[mt][jj][r0]);
          const float po = __builtin_amdgcn_exp2f(st[mt][jj][r0 + 1]);
          pf[mt][c2].w[w] = __builtin_amdgcn_perm(
              __float_as_uint(po), __float_as_uint(pe), 0x07060302u);
        }

#pragma unroll
    for (int c2 = 0; c2 < 2; ++c2) {
      lacc[0] = __builtin_amdgcn_mfma_f32_16x16x32_bf16(pf[0][c2].v, ones, lacc[0], 0, 0, 0);
      lacc[1] = __builtin_amdgcn_mfma_f32_16x16x32_bf16(pf[1][c2].v, ones, lacc[1], 0, 0, 0);
#pragma unroll
      for (int j = 0; j < 4; ++j) {
        const bf16x8 bv = *(const bf16x8*)&Vt[(j * 16 + c16) * 72 + c2 * 32 + quad * 8];
        ctx[0][j] = __builtin_amdgcn_mfma_f32_16x16x32_bf16(pf[0][c2].v, bv, ctx[0][j], 0, 0, 0);
        ctx[1][j] = __builtin_amdgcn_mfma_f32_16x16x32_bf16(pf[1][c2].v, bv, ctx[1][j], 0, 0, 0);
      }
    }
  }

#pragma unroll
  for (int mt = 0; mt < 2; ++mt) {
#pragma unroll
    for (int r = 0; r < 4; ++r) {
      const float inv = 1.f / lacc[mt][r];
      const int srow  = qt * 128 + wave * 32 + mt * 16 + quad * 4 + r;
      const size_t rb = ((size_t)(bb * Sc + srow)) * 1024 + hh * 64;
#pragma unroll
      for (int j = 0; j < 4; ++j)
        CTX[rb + j * 16 + c16] = f2bf(ctx[mt][j][r] * inv);
    }
  }
}

extern "C" void kernel_launch(void* const* d_in, const int* in_sizes, int n_in,
                              void* d_out, int out_size, void* d_ws, size_t ws_size,
                              hipStream_t stream) {
  (void)in_sizes; (void)n_in; (void)out_size; (void)ws_size;
  const float* x  = (const float*)d_in[0];
  const float* Wq = (const float*)d_in[1];
  const float* bq = (const float*)d_in[2];
  const float* Wk = (const float*)d_in[3];
  const float* bk = (const float*)d_in[4];
  const float* Wv = (const float*)d_in[5];
  const float* bv = (const float*)d_in[6];
  const float* Wo = (const float*)d_in[7];
  const float* bo = (const float*)d_in[8];

  const size_t MB = 1024 * 1024;
  char* w    = (char*)d_ws;
  ushort* Qw = (ushort*)(w + 0 * MB);   // [B,H,S,HD] bf16 (pre-scaled by EC)
  ushort* Kw = (ushort*)(w + 8 * MB);
  ushort* Vw = (ushort*)(w + 16 * MB);
  ushort* Cw = (ushort*)(w + 24 * MB);  // ctx [M,1024] bf16
  ushort* Xh = (ushort*)(w + 32 * MB);  // x bf16 [M,1024]
  ushort* WT = (ushort*)(w + 40 * MB);  // 8 x 2 MB
  ushort* Whq = WT + 0 * 1048576; ushort* Wlq = WT + 1 * 1048576;
  ushort* Whk = WT + 2 * 1048576; ushort* Wlk = WT + 3 * 1048576;
  ushort* Whv = WT + 4 * 1048576; ushort* Wlv = WT + 5 * 1048576;
  ushort* Who = WT + 6 * 1048576; ushort* Wlo = WT + 7 * 1048576;

  const dim3 blk(256);

  split_x_kernel<<<4096, blk, 0, stream>>>(x, Xh);

  SplitP sp;
  sp.W[0] = Wq; sp.W[1] = Wk; sp.W[2] = Wv; sp.W[3] = Wo;
  sp.Th[0] = Whq; sp.Th[1] = Whk; sp.Th[2] = Whv; sp.Th[3] = Who;
  sp.Tl[0] = Wlq; sp.Tl[1] = Wlk; sp.Tl[2] = Wlv; sp.Tl[3] = Wlo;
  split_wt_kernel<<<dim3(16, 16, 4), blk, 0, stream>>>(sp);

  GemmP pq;
  pq.Bh[0] = Whq; pq.Bh[1] = Whk; pq.Bh[2] = Whv;
  pq.Bl[0] = Wlq; pq.Bl[1] = Wlk; pq.Bl[2] = Wlv;
  pq.bias[0] = bq; pq.bias[1] = bk; pq.bias[2] = bv;
  pq.Out[0] = Qw; pq.Out[1] = Kw; pq.Out[2] = Vw;
  // grid.x = n-tiles (8) -> XCD = n%8, weights L2-resident per XCD
  gemm_bf16<true><<<dim3(Dc / 128, Mc / 128, 3), blk, 0, stream>>>(Xh, pq);

  attn_mfma3<<<dim3(2 * Hc, Sc / 128), blk, 0, stream>>>(Qw, Kw, Vw, Cw);

  GemmP po;
  po.Bh[0] = po.Bh[1] = po.Bh[2] = Who;
  po.Bl[0] = po.Bl[1] = po.Bl[2] = Wlo;  // unused (1-product)
  po.bias[0] = po.bias[1] = po.bias[2] = bo;
  po.Out[0] = po.Out[1] = po.Out[2] = d_out;
  gemm_bf16<false><<<dim3(Dc / 128, Mc / 64, 1), blk, 0, stream>>>(Cw, po);
}